// Round 1
// baseline (692.353 us; speedup 1.0000x reference)
//
#include <hip/hip_runtime.h>

#define UNITS 16
#define DIMS 272            // 16 + 16*16
#define NV4 68              // DIMS / 4 float4 per row

__global__ __launch_bounds__(256) void linear_pair_gemv(
    const float* __restrict__ in,     // [N, 272] row-major
    const float* __restrict__ kern,   // [16]
    const float* __restrict__ w1p,    // [1]
    const float* __restrict__ w2p,    // [1]
    const float* __restrict__ biasp,  // [1]
    float* __restrict__ out,          // [N]
    int N)
{
    __shared__ __align__(16) float sw[DIMS];

    const int t = threadIdx.x;

    // ---- build the 272 weights in LDS (once per block) ----
    {
        const float w1 = w1p[0];
        const float w2 = w2p[0];
        for (int j = t; j < DIMS; j += 256) {
            float v;
            if (j < UNITS) {
                v = kern[j];
            } else {
                const int p  = j - UNITS;     // 0..255
                const int x1 = p >> 4;        // 0..15
                const int x2 = p & 15;        // 0..15
                const int a1 = x1 >> 2, b1 = x1 & 3;
                const int a2 = x2 >> 2, b2 = x2 & 3;
                v = kern[4 * a1 + a2] * kern[4 * b1 + b2] * w1
                  + kern[4 * a1 + b2] * kern[4 * b1 + a2] * w2;
            }
            sw[j] = v;
        }
    }
    __syncthreads();

    const float bias = biasp[0];

    const int lane  = t & 63;
    const int wave  = t >> 6;                        // 0..3
    const int gwave = blockIdx.x * 4 + wave;
    const int nwaves = gridDim.x * 4;

    // per-lane weight fragments, held in registers across the whole loop
    const float4* swv = (const float4*)sw;
    const float4 wv = swv[lane];                     // float4 #lane (0..63)
    float4 wt = make_float4(0.f, 0.f, 0.f, 0.f);
    if (lane < 4) wt = swv[64 + lane];               // tail float4 #64..67

    for (int row = gwave; row < N; row += nwaves) {
        const float4* rp = (const float4*)(in + (size_t)row * DIMS);
        float4 x = rp[lane];                         // 1024 contiguous bytes/wave
        float partial = x.x * wv.x + x.y * wv.y + x.z * wv.z + x.w * wv.w;
        if (lane < 4) {
            float4 xt = rp[64 + lane];               // 64-byte tail
            partial += xt.x * wt.x + xt.y * wt.y + xt.z * wt.z + xt.w * wt.w;
        }
        // wave-64 reduction
        #pragma unroll
        for (int off = 32; off > 0; off >>= 1)
            partial += __shfl_down(partial, off, 64);
        if (lane == 0) out[row] = partial + bias;
    }
}

extern "C" void kernel_launch(void* const* d_in, const int* in_sizes, int n_in,
                              void* d_out, int out_size, void* d_ws, size_t ws_size,
                              hipStream_t stream) {
    const float* in    = (const float*)d_in[0];
    const float* kern  = (const float*)d_in[1];
    const float* w1p   = (const float*)d_in[2];
    const float* w2p   = (const float*)d_in[3];
    const float* biasp = (const float*)d_in[4];
    float* out         = (float*)d_out;

    const int N = in_sizes[0] / DIMS;   // 500000

    const int blocks = 2048;            // 8 blocks/CU, 32 waves/CU
    linear_pair_gemv<<<blocks, 256, 0, stream>>>(in, kern, w1p, w2p, biasp, out, N);
}